// Round 6
// baseline (10394.283 us; speedup 1.0000x reference)
//
#include <hip/hip_runtime.h>

// SpikeLinear: out = LIF_scan( x @ W^T + bias ) over T=8 timesteps.
//
// Numerics (DO NOT CHANGE): must reproduce numpy/OpenBLAS sgemm bit-for-bit
// because the spike threshold (memb > 1.0) is discontinuous. OpenBLAS
// accumulates each C element as a strict sequential fp32 FMA chain over
// ascending k, blocked by kc=384: per-panel register accumulation from zero,
// then C += panel (fp32 add) at k = 384, 768, ..., 3840, then fp32 bias add
// and fp32 LIF scan. Verified absmax == 0.0 in round 3.
//
// Perf lineage:
//  r3: 4-col tile, 2 barriers/step, single-buffer LDS -> 851us, VGPR 64,
//      no scratch, VALUBusy 70%.
//  r4/r5: 8-col tile variants -> compiler spills acc around every loop iter
//      (126KB/thread scratch, 5.3ms). Lesson: 8-col + 48 clustered ds_reads
//      exceeds the register cap; do NOT widen the tile.
//  r6 (this): r3 + double-buffered LDS (ONE barrier/step) + global prefetch
//      hidden under the FMA block. Only change from r3.

constexpr int TSTEPS = 8;
constexpr int BK     = 16;
constexpr int TILE_M = 64;    // 8 batches * 8 timesteps
constexpr int TILE_N = 128;   // output columns per block
constexpr int FOLD_S = 24;    // BK-steps per kc panel: 24*16 = 384 = OpenBLAS kc

__global__ __launch_bounds__(256, 4)
void spike_linear_f32seq(const float* __restrict__ x,
                         const float* __restrict__ w,
                         const float* __restrict__ bias,
                         float* __restrict__ out,
                         int B, int IN, int OUT)
{
    // k-major LDS tiles, double-buffered. +4 pad keeps rows 16B-aligned.
    __shared__ float xs[2][BK][TILE_M + 4];
    __shared__ float ws[2][BK][TILE_N + 4];

    const int tid = threadIdx.x;
    const int tx  = tid & 31;    // column group: 4 consecutive outputs
    const int ty  = tid >> 5;    // batch row within tile (owns all 8 t)

    const int m0 = blockIdx.y * TILE_M;
    const int n0 = blockIdx.x * TILE_N;

    float acc_tot[TSTEPS][4];    // C memory value (panel sums folded in)
    float acc_blk[TSTEPS][4];    // current kc-panel register accumulator
    #pragma unroll
    for (int t = 0; t < TSTEPS; ++t)
        #pragma unroll
        for (int c = 0; c < 4; ++c) { acc_tot[t][c] = 0.f; acc_blk[t][c] = 0.f; }

    // staging: thread -> (row sr, k-offset sk); one float4 of x, two of w
    const int sr = tid >> 2;         // 0..63
    const int sk = (tid & 3) * 4;    // 0,4,8,12

    const float* xrow  = x + (size_t)(m0 + sr) * IN + sk;
    const float* wrow0 = w + (size_t)(n0 + sr) * IN + sk;
    const float* wrow1 = w + (size_t)(n0 + 64 + sr) * IN + sk;

    // prologue: stage k-step 0 into buffer 0
    {
        const float4 xv  = *(const float4*)(xrow);
        const float4 wv0 = *(const float4*)(wrow0);
        const float4 wv1 = *(const float4*)(wrow1);
        xs[0][sk+0][sr] = xv.x;  xs[0][sk+1][sr] = xv.y;
        xs[0][sk+2][sr] = xv.z;  xs[0][sk+3][sr] = xv.w;
        ws[0][sk+0][sr]    = wv0.x; ws[0][sk+1][sr]    = wv0.y;
        ws[0][sk+2][sr]    = wv0.z; ws[0][sk+3][sr]    = wv0.w;
        ws[0][sk+0][sr+64] = wv1.x; ws[0][sk+1][sr+64] = wv1.y;
        ws[0][sk+2][sr+64] = wv1.z; ws[0][sk+3][sr+64] = wv1.w;
    }
    __syncthreads();

    const int NS = IN / BK;          // 256 steps
    int next_fold = FOLD_S;          // s = 24, 48, ..., 240

    for (int s = 0; s < NS; ++s) {
        const int buf = s & 1;
        const bool hn = (s + 1) < NS;

        // prefetch next k-step from global (latency hides under the FMAs)
        float4 xv, wv0, wv1;
        if (hn) {
            const int ko = (s + 1) * BK;
            xv  = *(const float4*)(xrow  + ko);
            wv0 = *(const float4*)(wrow0 + ko);
            wv1 = *(const float4*)(wrow1 + ko);
        }

        // kc-panel boundary: fold panel into C exactly like BLAS (C += panel)
        if (s == next_fold) {
            next_fold += FOLD_S;
            #pragma unroll
            for (int t = 0; t < TSTEPS; ++t)
                #pragma unroll
                for (int c = 0; c < 4; ++c) {
                    acc_tot[t][c] += acc_blk[t][c];
                    acc_blk[t][c] = 0.f;
                }
        }

        #pragma unroll
        for (int k = 0; k < BK; ++k) {
            float xr[TSTEPS];
            *(float4*)&xr[0] = *(const float4*)&xs[buf][k][ty*8];
            *(float4*)&xr[4] = *(const float4*)&xs[buf][k][ty*8 + 4];
            float wr[4];
            *(float4*)&wr[0] = *(const float4*)&ws[buf][k][tx*4];
            #pragma unroll
            for (int t = 0; t < TSTEPS; ++t)
                #pragma unroll
                for (int c = 0; c < 4; ++c)
                    acc_blk[t][c] = fmaf(xr[t], wr[c], acc_blk[t][c]);
        }

        if (hn) {
            const int nb = buf ^ 1;
            xs[nb][sk+0][sr] = xv.x;  xs[nb][sk+1][sr] = xv.y;
            xs[nb][sk+2][sr] = xv.z;  xs[nb][sk+3][sr] = xv.w;
            ws[nb][sk+0][sr]    = wv0.x; ws[nb][sk+1][sr]    = wv0.y;
            ws[nb][sk+2][sr]    = wv0.z; ws[nb][sk+3][sr]    = wv0.w;
            ws[nb][sk+0][sr+64] = wv1.x; ws[nb][sk+1][sr+64] = wv1.y;
            ws[nb][sk+2][sr+64] = wv1.z; ws[nb][sk+3][sr+64] = wv1.w;
        }
        __syncthreads();
    }

    // final panel fold (last panel is 256 wide: 4096 = 10*384 + 256)
    #pragma unroll
    for (int t = 0; t < TSTEPS; ++t)
        #pragma unroll
        for (int c = 0; c < 4; ++c)
            acc_tot[t][c] += acc_blk[t][c];

    // epilogue: fp32 bias add (numpy order), fp32 LIF scan.
    const int bg = blockIdx.y * 8 + ty;   // global batch index
    const int o0 = n0 + tx * 4;
    const float4 bv = *(const float4*)(bias + o0);
    const float bb[4] = {bv.x, bv.y, bv.z, bv.w};
    float memb[4] = {0.f, 0.f, 0.f, 0.f};
    #pragma unroll
    for (int t = 0; t < TSTEPS; ++t) {
        float4 sp;
        float* spp = (float*)&sp;
        #pragma unroll
        for (int c = 0; c < 4; ++c) {
            float pre = acc_tot[t][c] + bb[c];
            memb[c] += pre;                          // VTHR = 1.0 (exact)
            float s = (memb[c] > 1.0f) ? 1.0f : 0.0f;
            memb[c] *= (1.0f - s);                   // reset to zero
            spp[c] = s;
        }
        *(float4*)(out + ((size_t)t * B + bg) * OUT + o0) = sp;
    }
}

extern "C" void kernel_launch(void* const* d_in, const int* in_sizes, int n_in,
                              void* d_out, int out_size, void* d_ws, size_t ws_size,
                              hipStream_t stream)
{
    const float* x    = (const float*)d_in[0];
    const float* w    = (const float*)d_in[1];
    const float* bias = (const float*)d_in[2];
    float* out = (float*)d_out;

    const int OUT = in_sizes[2];            // 4096
    const int IN  = in_sizes[1] / OUT;      // 4096
    const int BT  = in_sizes[0] / IN;       // 2048
    const int B   = BT / TSTEPS;            // 256

    dim3 grid(OUT / TILE_N, BT / TILE_M);   // (32, 32) = 1024 blocks = 4/CU
    spike_linear_f32seq<<<grid, 256, 0, stream>>>(x, w, bias, out, B, IN, OUT);
}

// Round 7
// 1123.177 us; speedup vs baseline: 9.2544x; 9.2544x over previous
//
#include <hip/hip_runtime.h>

// SpikeLinear: out = LIF_scan( x @ W^T + bias ) over T=8 timesteps.
//
// Numerics (DO NOT CHANGE): must reproduce numpy/OpenBLAS sgemm bit-for-bit
// because the spike threshold (memb > 1.0) is discontinuous. OpenBLAS
// accumulates each C element as a strict sequential fp32 FMA chain over
// ascending k, blocked by kc=384: per-panel register accumulation from zero,
// then C += panel (fp32 add) at k = 384, 768, ..., 3840, then fp32 bias add
// and fp32 LIF scan. Verified absmax == 0.0 in round 3.
//
// Perf lineage:
//  r3: 4-col tile, 2 barriers/step, single-buffer LDS, (256,4) -> 851us,
//      VGPR 64, no spill, VALUBusy 70%.
//  r4/r5: 8-col tile -> 128 acc floats + working set > 128-reg cap -> spill.
//  r6: r3 + dbuf/prefetch under (256,4): the (256,4) bound empirically caps
//      VGPRs at 64; prefetch regs live across the FMA block pushed peak live
//      ~75 > 64 -> acc_blk spilled EVERY step (33 GB scratch writes, 10.4ms).
//  r7 (this): r6 with (256,2) -> 128-VGPR cap (empirical from r4/r5).
//      Live set ~80 < 128. ONLY the launch bound changes vs r6.

constexpr int TSTEPS = 8;
constexpr int BK     = 16;
constexpr int TILE_M = 64;    // 8 batches * 8 timesteps
constexpr int TILE_N = 128;   // output columns per block
constexpr int FOLD_S = 24;    // BK-steps per kc panel: 24*16 = 384 = OpenBLAS kc

__global__ __launch_bounds__(256, 2)
void spike_linear_f32seq(const float* __restrict__ x,
                         const float* __restrict__ w,
                         const float* __restrict__ bias,
                         float* __restrict__ out,
                         int B, int IN, int OUT)
{
    // k-major LDS tiles, double-buffered. +4 pad keeps rows 16B-aligned.
    __shared__ float xs[2][BK][TILE_M + 4];
    __shared__ float ws[2][BK][TILE_N + 4];

    const int tid = threadIdx.x;
    const int tx  = tid & 31;    // column group: 4 consecutive outputs
    const int ty  = tid >> 5;    // batch row within tile (owns all 8 t)

    const int m0 = blockIdx.y * TILE_M;
    const int n0 = blockIdx.x * TILE_N;

    float acc_tot[TSTEPS][4];    // C memory value (panel sums folded in)
    float acc_blk[TSTEPS][4];    // current kc-panel register accumulator
    #pragma unroll
    for (int t = 0; t < TSTEPS; ++t)
        #pragma unroll
        for (int c = 0; c < 4; ++c) { acc_tot[t][c] = 0.f; acc_blk[t][c] = 0.f; }

    // staging: thread -> (row sr, k-offset sk); one float4 of x, two of w
    const int sr = tid >> 2;         // 0..63
    const int sk = (tid & 3) * 4;    // 0,4,8,12

    const float* xrow  = x + (size_t)(m0 + sr) * IN + sk;
    const float* wrow0 = w + (size_t)(n0 + sr) * IN + sk;
    const float* wrow1 = w + (size_t)(n0 + 64 + sr) * IN + sk;

    // prologue: stage k-step 0 into buffer 0
    {
        const float4 xv  = *(const float4*)(xrow);
        const float4 wv0 = *(const float4*)(wrow0);
        const float4 wv1 = *(const float4*)(wrow1);
        xs[0][sk+0][sr] = xv.x;  xs[0][sk+1][sr] = xv.y;
        xs[0][sk+2][sr] = xv.z;  xs[0][sk+3][sr] = xv.w;
        ws[0][sk+0][sr]    = wv0.x; ws[0][sk+1][sr]    = wv0.y;
        ws[0][sk+2][sr]    = wv0.z; ws[0][sk+3][sr]    = wv0.w;
        ws[0][sk+0][sr+64] = wv1.x; ws[0][sk+1][sr+64] = wv1.y;
        ws[0][sk+2][sr+64] = wv1.z; ws[0][sk+3][sr+64] = wv1.w;
    }
    __syncthreads();

    const int NS = IN / BK;          // 256 steps
    int next_fold = FOLD_S;          // s = 24, 48, ..., 240

    for (int s = 0; s < NS; ++s) {
        const int buf = s & 1;
        const bool hn = (s + 1) < NS;

        // prefetch next k-step from global (latency hides under the FMAs)
        float4 xv, wv0, wv1;
        if (hn) {
            const int ko = (s + 1) * BK;
            xv  = *(const float4*)(xrow  + ko);
            wv0 = *(const float4*)(wrow0 + ko);
            wv1 = *(const float4*)(wrow1 + ko);
        }

        // kc-panel boundary: fold panel into C exactly like BLAS (C += panel)
        if (s == next_fold) {
            next_fold += FOLD_S;
            #pragma unroll
            for (int t = 0; t < TSTEPS; ++t)
                #pragma unroll
                for (int c = 0; c < 4; ++c) {
                    acc_tot[t][c] += acc_blk[t][c];
                    acc_blk[t][c] = 0.f;
                }
        }

        #pragma unroll
        for (int k = 0; k < BK; ++k) {
            float xr[TSTEPS];
            *(float4*)&xr[0] = *(const float4*)&xs[buf][k][ty*8];
            *(float4*)&xr[4] = *(const float4*)&xs[buf][k][ty*8 + 4];
            float wr[4];
            *(float4*)&wr[0] = *(const float4*)&ws[buf][k][tx*4];
            #pragma unroll
            for (int t = 0; t < TSTEPS; ++t)
                #pragma unroll
                for (int c = 0; c < 4; ++c)
                    acc_blk[t][c] = fmaf(xr[t], wr[c], acc_blk[t][c]);
        }

        if (hn) {
            const int nb = buf ^ 1;
            xs[nb][sk+0][sr] = xv.x;  xs[nb][sk+1][sr] = xv.y;
            xs[nb][sk+2][sr] = xv.z;  xs[nb][sk+3][sr] = xv.w;
            ws[nb][sk+0][sr]    = wv0.x; ws[nb][sk+1][sr]    = wv0.y;
            ws[nb][sk+2][sr]    = wv0.z; ws[nb][sk+3][sr]    = wv0.w;
            ws[nb][sk+0][sr+64] = wv1.x; ws[nb][sk+1][sr+64] = wv1.y;
            ws[nb][sk+2][sr+64] = wv1.z; ws[nb][sk+3][sr+64] = wv1.w;
        }
        __syncthreads();
    }

    // final panel fold (last panel is 256 wide: 4096 = 10*384 + 256)
    #pragma unroll
    for (int t = 0; t < TSTEPS; ++t)
        #pragma unroll
        for (int c = 0; c < 4; ++c)
            acc_tot[t][c] += acc_blk[t][c];

    // epilogue: fp32 bias add (numpy order), fp32 LIF scan.
    const int bg = blockIdx.y * 8 + ty;   // global batch index
    const int o0 = n0 + tx * 4;
    const float4 bv = *(const float4*)(bias + o0);
    const float bb[4] = {bv.x, bv.y, bv.z, bv.w};
    float memb[4] = {0.f, 0.f, 0.f, 0.f};
    #pragma unroll
    for (int t = 0; t < TSTEPS; ++t) {
        float4 sp;
        float* spp = (float*)&sp;
        #pragma unroll
        for (int c = 0; c < 4; ++c) {
            float pre = acc_tot[t][c] + bb[c];
            memb[c] += pre;                          // VTHR = 1.0 (exact)
            float s = (memb[c] > 1.0f) ? 1.0f : 0.0f;
            memb[c] *= (1.0f - s);                   // reset to zero
            spp[c] = s;
        }
        *(float4*)(out + ((size_t)t * B + bg) * OUT + o0) = sp;
    }
}

extern "C" void kernel_launch(void* const* d_in, const int* in_sizes, int n_in,
                              void* d_out, int out_size, void* d_ws, size_t ws_size,
                              hipStream_t stream)
{
    const float* x    = (const float*)d_in[0];
    const float* w    = (const float*)d_in[1];
    const float* bias = (const float*)d_in[2];
    float* out = (float*)d_out;

    const int OUT = in_sizes[2];            // 4096
    const int IN  = in_sizes[1] / OUT;      // 4096
    const int BT  = in_sizes[0] / IN;       // 2048
    const int B   = BT / TSTEPS;            // 256

    dim3 grid(OUT / TILE_N, BT / TILE_M);   // (32, 32) = 1024 blocks = 4/CU
    spike_linear_f32seq<<<grid, 256, 0, stream>>>(x, w, bias, out, B, IN, OUT);
}

// Round 8
// 852.052 us; speedup vs baseline: 12.1991x; 1.3182x over previous
//
#include <hip/hip_runtime.h>

// SpikeLinear: out = LIF_scan( x @ W^T + bias ) over T=8 timesteps.
//
// Numerics (DO NOT CHANGE): must reproduce numpy/OpenBLAS sgemm bit-for-bit
// because the spike threshold (memb > 1.0) is discontinuous. OpenBLAS
// accumulates each C element as a strict sequential fp32 FMA chain over
// ascending k, blocked by kc=384: each panel accumulates from zero in
// registers, then C += panel (fp32 add) in ascending panel order, then fp32
// bias add and fp32 LIF scan. Verified absmax == 0.0 in round 3.
//
// Perf lineage:
//  r3: 4-col tile, 2-barrier single-buffer LDS, (256,4) -> 851us, VGPR 64,
//      no spill, VALUBusy 70%, occupancy 33% (GRID-STARVED: 1024 blocks =
//      16 waves/CU vs 32 possible at VGPR 64).
//  r4-r7: all register-pressure/pipelining attempts regressed. Lesson:
//      keep the r3 inner loop EXACTLY; the lever is occupancy.
//  r8 (this): K-split at kc panel boundaries (the only legal split points).
//      Phase 1: 11 independent panel GEMMs, grid 32x32x11 = 11264 blocks ->
//      8 blocks/CU resident (2x waves vs r3), r3 inner loop minus fold logic.
//      Panels 0..9 -> d_ws (m-major rows b*8+t); panel 10 -> out using the
//      SPIKE row mapping (t*B+b) so phase 2's reader thread == writer thread.
//      Phase 2: fold panels in exact BLAS order + bias + LIF scan (~400MB,
//      memory-bound). Fallback to the verified r3 kernel if ws is too small.

constexpr int TSTEPS = 8;
constexpr int BK     = 16;
constexpr int TILE_M = 64;    // 8 batches * 8 timesteps
constexpr int TILE_N = 128;   // output columns per block
constexpr int KC     = 384;   // OpenBLAS SGEMM_DEFAULT_Q on x86-64
constexpr int FOLD_S = KC / BK;

// ---------------------------------------------------------------- phase 1 --
__global__ __launch_bounds__(256, 4)
void spike_panel_gemm(const float* __restrict__ x,
                      const float* __restrict__ w,
                      const float* __restrict__ bias,   // unused, kept for symmetry
                      float* __restrict__ panels,       // ws: panels 0..np-2
                      float* __restrict__ out,          // holds last panel
                      int B, int IN, int OUT, int npanels)
{
    __shared__ float xs[BK][TILE_M + 4];
    __shared__ float wsh[BK][TILE_N + 4];

    const int tid = threadIdx.x;
    const int tx  = tid & 31;    // column group: 4 consecutive outputs
    const int ty  = tid >> 5;    // batch row within tile (owns all 8 t)

    const int m0 = blockIdx.y * TILE_M;
    const int n0 = blockIdx.x * TILE_N;
    const int p  = blockIdx.z;
    const int ks = p * KC;
    const int ke = (ks + KC < IN) ? (ks + KC) : IN;

    float acc[TSTEPS][4];        // this panel's accumulator (from zero)
    #pragma unroll
    for (int t = 0; t < TSTEPS; ++t)
        #pragma unroll
        for (int c = 0; c < 4; ++c) acc[t][c] = 0.f;

    // staging: thread -> (row sr, k-offset sk); one float4 of x, two of w
    const int sr = tid >> 2;         // 0..63
    const int sk = (tid & 3) * 4;    // 0,4,8,12

    const float* xrow  = x + (size_t)(m0 + sr) * IN + sk;
    const float* wrow0 = w + (size_t)(n0 + sr) * IN + sk;
    const float* wrow1 = w + (size_t)(n0 + 64 + sr) * IN + sk;

    for (int kk = ks; kk < ke; kk += BK) {
        const float4 xv  = *(const float4*)(xrow  + kk);
        const float4 wv0 = *(const float4*)(wrow0 + kk);
        const float4 wv1 = *(const float4*)(wrow1 + kk);
        __syncthreads();
        xs[sk+0][sr] = xv.x;  xs[sk+1][sr] = xv.y;
        xs[sk+2][sr] = xv.z;  xs[sk+3][sr] = xv.w;
        wsh[sk+0][sr]    = wv0.x; wsh[sk+1][sr]    = wv0.y;
        wsh[sk+2][sr]    = wv0.z; wsh[sk+3][sr]    = wv0.w;
        wsh[sk+0][sr+64] = wv1.x; wsh[sk+1][sr+64] = wv1.y;
        wsh[sk+2][sr+64] = wv1.z; wsh[sk+3][sr+64] = wv1.w;
        __syncthreads();

        #pragma unroll
        for (int k = 0; k < BK; ++k) {
            float xr[TSTEPS];
            *(float4*)&xr[0] = *(const float4*)&xs[k][ty*8];
            *(float4*)&xr[4] = *(const float4*)&xs[k][ty*8 + 4];
            float wr[4];
            *(float4*)&wr[0] = *(const float4*)&wsh[k][tx*4];
            #pragma unroll
            for (int t = 0; t < TSTEPS; ++t)
                #pragma unroll
                for (int c = 0; c < 4; ++c)
                    acc[t][c] = fmaf(xr[t], wr[c], acc[t][c]);
        }
    }

    const int bg = blockIdx.y * 8 + ty;   // global batch index
    const int o0 = n0 + tx * 4;
    if (p < npanels - 1) {
        // panels 0..np-2: m-major rows (b*8 + t), slot p in ws
        float* pb = panels + (size_t)p * B * TSTEPS * OUT;
        #pragma unroll
        for (int t = 0; t < TSTEPS; ++t) {
            const int m = bg * TSTEPS + t;            // == m0 + ty*8 + t
            *(float4*)(pb + (size_t)m * OUT + o0) = *(float4*)&acc[t][0];
        }
    } else {
        // last panel lives in `out` with the SPIKE row mapping (t*B + b) so
        // that in phase 2 the thread that reads it is the thread that
        // overwrites it (no cross-thread hazard).
        #pragma unroll
        for (int t = 0; t < TSTEPS; ++t)
            *(float4*)(out + ((size_t)t * B + bg) * OUT + o0) = *(float4*)&acc[t][0];
    }
}

// ---------------------------------------------------------------- phase 2 --
__global__ __launch_bounds__(256)
void spike_fold_scan(const float* __restrict__ panels,
                     const float* __restrict__ bias,
                     float* __restrict__ out,
                     int B, int OUT, int npanels)
{
    const int col = blockIdx.x * 1024 + threadIdx.x * 4;
    const int b   = blockIdx.y;
    const size_t psz = (size_t)B * TSTEPS * OUT;

    // v[t] = panel0, then += panel1 ... += panel(np-2) (exact BLAS order)
    float4 v[TSTEPS];
    #pragma unroll
    for (int t = 0; t < TSTEPS; ++t)
        v[t] = *(const float4*)(panels + (size_t)(b*TSTEPS + t) * OUT + col);
    for (int p = 1; p < npanels - 1; ++p) {
        const float* pb = panels + (size_t)p * psz;
        #pragma unroll
        for (int t = 0; t < TSTEPS; ++t) {
            const float4 u = *(const float4*)(pb + (size_t)(b*TSTEPS + t) * OUT + col);
            v[t].x += u.x; v[t].y += u.y; v[t].z += u.z; v[t].w += u.w;
        }
    }
    // last panel from out (spike-layout rows, owned by this thread)
    #pragma unroll
    for (int t = 0; t < TSTEPS; ++t) {
        const float4 u = *(const float4*)(out + ((size_t)t * B + b) * OUT + col);
        v[t].x += u.x; v[t].y += u.y; v[t].z += u.z; v[t].w += u.w;
    }

    const float4 bb = *(const float4*)(bias + col);
    float memb[4] = {0.f, 0.f, 0.f, 0.f};
    #pragma unroll
    for (int t = 0; t < TSTEPS; ++t) {
        float pre[4] = {v[t].x + bb.x, v[t].y + bb.y, v[t].z + bb.z, v[t].w + bb.w};
        float4 sp;
        float* spp = (float*)&sp;
        #pragma unroll
        for (int c = 0; c < 4; ++c) {
            memb[c] += pre[c];                       // VTHR = 1.0 (exact)
            float s = (memb[c] > 1.0f) ? 1.0f : 0.0f;
            memb[c] *= (1.0f - s);                   // reset to zero
            spp[c] = s;
        }
        *(float4*)(out + ((size_t)t * B + b) * OUT + col) = sp;
    }
}

// ------------------------------------------------- fallback: r3 (verified) --
__global__ __launch_bounds__(256, 4)
void spike_linear_f32seq(const float* __restrict__ x,
                         const float* __restrict__ w,
                         const float* __restrict__ bias,
                         float* __restrict__ out,
                         int B, int IN, int OUT)
{
    __shared__ float xs[BK][TILE_M + 4];
    __shared__ float ws[BK][TILE_N + 4];

    const int tid = threadIdx.x;
    const int tx  = tid & 31;
    const int ty  = tid >> 5;

    const int m0 = blockIdx.y * TILE_M;
    const int n0 = blockIdx.x * TILE_N;

    float acc_tot[TSTEPS][4];
    float acc_blk[TSTEPS][4];
    #pragma unroll
    for (int t = 0; t < TSTEPS; ++t)
        #pragma unroll
        for (int c = 0; c < 4; ++c) { acc_tot[t][c] = 0.f; acc_blk[t][c] = 0.f; }

    const int sr = tid >> 2;
    const int sk = (tid & 3) * 4;

    const float* xrow  = x + (size_t)(m0 + sr) * IN + sk;
    const float* wrow0 = w + (size_t)(n0 + sr) * IN + sk;
    const float* wrow1 = w + (size_t)(n0 + 64 + sr) * IN + sk;

    for (int kk = 0; kk < IN; kk += BK) {
        if (kk > 0 && (kk % KC) == 0) {
            #pragma unroll
            for (int t = 0; t < TSTEPS; ++t)
                #pragma unroll
                for (int c = 0; c < 4; ++c) {
                    acc_tot[t][c] += acc_blk[t][c];
                    acc_blk[t][c] = 0.f;
                }
        }
        const float4 xv  = *(const float4*)(xrow  + kk);
        const float4 wv0 = *(const float4*)(wrow0 + kk);
        const float4 wv1 = *(const float4*)(wrow1 + kk);
        __syncthreads();
        xs[sk+0][sr] = xv.x;  xs[sk+1][sr] = xv.y;
        xs[sk+2][sr] = xv.z;  xs[sk+3][sr] = xv.w;
        ws[sk+0][sr]    = wv0.x; ws[sk+1][sr]    = wv0.y;
        ws[sk+2][sr]    = wv0.z; ws[sk+3][sr]    = wv0.w;
        ws[sk+0][sr+64] = wv1.x; ws[sk+1][sr+64] = wv1.y;
        ws[sk+2][sr+64] = wv1.z; ws[sk+3][sr+64] = wv1.w;
        __syncthreads();

        #pragma unroll
        for (int k = 0; k < BK; ++k) {
            float xr[TSTEPS];
            *(float4*)&xr[0] = *(const float4*)&xs[k][ty*8];
            *(float4*)&xr[4] = *(const float4*)&xs[k][ty*8 + 4];
            float wr[4];
            *(float4*)&wr[0] = *(const float4*)&ws[k][tx*4];
            #pragma unroll
            for (int t = 0; t < TSTEPS; ++t)
                #pragma unroll
                for (int c = 0; c < 4; ++c)
                    acc_blk[t][c] = fmaf(xr[t], wr[c], acc_blk[t][c]);
        }
    }
    #pragma unroll
    for (int t = 0; t < TSTEPS; ++t)
        #pragma unroll
        for (int c = 0; c < 4; ++c)
            acc_tot[t][c] += acc_blk[t][c];

    const int bg = blockIdx.y * 8 + ty;
    const int o0 = n0 + tx * 4;
    const float4 bv = *(const float4*)(bias + o0);
    const float bb[4] = {bv.x, bv.y, bv.z, bv.w};
    float memb[4] = {0.f, 0.f, 0.f, 0.f};
    #pragma unroll
    for (int t = 0; t < TSTEPS; ++t) {
        float4 sp;
        float* spp = (float*)&sp;
        #pragma unroll
        for (int c = 0; c < 4; ++c) {
            float pre = acc_tot[t][c] + bb[c];
            memb[c] += pre;
            float s = (memb[c] > 1.0f) ? 1.0f : 0.0f;
            memb[c] *= (1.0f - s);
            spp[c] = s;
        }
        *(float4*)(out + ((size_t)t * B + bg) * OUT + o0) = sp;
    }
}

extern "C" void kernel_launch(void* const* d_in, const int* in_sizes, int n_in,
                              void* d_out, int out_size, void* d_ws, size_t ws_size,
                              hipStream_t stream)
{
    const float* x    = (const float*)d_in[0];
    const float* w    = (const float*)d_in[1];
    const float* bias = (const float*)d_in[2];
    float* out = (float*)d_out;

    const int OUT = in_sizes[2];            // 4096
    const int IN  = in_sizes[1] / OUT;      // 4096
    const int BT  = in_sizes[0] / IN;       // 2048
    const int B   = BT / TSTEPS;            // 256

    const int npanels = (IN + KC - 1) / KC; // 11
    const size_t need = (size_t)(npanels - 1) * BT * OUT * sizeof(float); // 335.5 MB

    if (ws_size >= need && (OUT % 1024) == 0) {
        float* panels = (float*)d_ws;
        dim3 g1(OUT / TILE_N, BT / TILE_M, npanels);   // (32, 32, 11)
        spike_panel_gemm<<<g1, 256, 0, stream>>>(x, w, bias, panels, out,
                                                 B, IN, OUT, npanels);
        dim3 g2(OUT / 1024, B);                        // (4, 256)
        spike_fold_scan<<<g2, 256, 0, stream>>>(panels, bias, out, B, OUT, npanels);
    } else {
        dim3 grid(OUT / TILE_N, BT / TILE_M);          // (32, 32)
        spike_linear_f32seq<<<grid, 256, 0, stream>>>(x, w, bias, out, B, IN, OUT);
    }
}